// Round 1
// baseline (843.394 us; speedup 1.0000x reference)
//
#include <hip/hip_runtime.h>
#include <hip/hip_bf16.h>

#define NN 8192
#define FIN 256
#define FOUT 64

// K1: Wh = H@W + bW; s_src = Wh.a1 + a_b; t = Wh.a2; exps + interleaved PP.
__global__ __launch_bounds__(256) void k1_proj(
    const float* __restrict__ H, const float* __restrict__ W,
    const float* __restrict__ bW, const float* __restrict__ aw,
    const float* __restrict__ ab,
    float* __restrict__ Wh, float* __restrict__ s_src, float* __restrict__ t_tar,
    float* __restrict__ E1, float* __restrict__ E2, float* __restrict__ PP)
{
    __shared__ float Hs[16 * FIN];
    int tid = threadIdx.x;
    int i0 = blockIdx.x * 16;
    const float4* Hv = (const float4*)(H + (size_t)i0 * FIN);
    float4* Hsv = (float4*)Hs;
    for (int idx = tid; idx < 16 * FIN / 4; idx += 256) Hsv[idx] = Hv[idx];
    __syncthreads();
    int f = tid & 63, sub = tid >> 6;
    float a1f = aw[f], a2f = aw[64 + f];
    float b = bW[f];
    float acc0 = b, acc1 = b, acc2 = b, acc3 = b;
    for (int k = 0; k < FIN; ++k) {
        float w = W[k * FOUT + f];
        acc0 += Hs[(sub     ) * FIN + k] * w;
        acc1 += Hs[(sub +  4) * FIN + k] * w;
        acc2 += Hs[(sub +  8) * FIN + k] * w;
        acc3 += Hs[(sub + 12) * FIN + k] * w;
    }
    float accs[4] = {acc0, acc1, acc2, acc3};
    #pragma unroll
    for (int q = 0; q < 4; ++q) {
        int i = i0 + sub + 4 * q;
        float a = accs[q];
        Wh[(size_t)i * FOUT + f] = a;
        float v1 = a * a1f, v2 = a * a2f;
        #pragma unroll
        for (int o = 32; o > 0; o >>= 1) {
            v1 += __shfl_xor(v1, o);
            v2 += __shfl_xor(v2, o);
        }
        if (f == 0) {
            float s = v1 + ab[0];   // fold a_b into the row score
            float t = v2;
            s_src[i] = s; t_tar[i] = t;
            E1[i] = __expf(s); E2[i] = __expf(0.01f * s);
            PP[2 * i]     = __expf(t);
            PP[2 * i + 1] = __expf(0.01f * t);
        }
    }
}

// K2: rank each t_j (ties by index) -> permutation; k_i = #{j : t_j < -s_i}.
__global__ __launch_bounds__(256) void k2_rank(
    const float* __restrict__ t_tar, const float* __restrict__ s_src,
    int* __restrict__ sorted_idx, int* __restrict__ kidx)
{
    __shared__ float Ts[256];
    int g = blockIdx.x * 256 + threadIdx.x;
    float tj = t_tar[g];
    float thr = -s_src[g];
    int rank = 0, kc = 0;
    for (int base = 0; base < NN; base += 256) {
        Ts[threadIdx.x] = t_tar[base + threadIdx.x];
        __syncthreads();
        #pragma unroll 8
        for (int kk = 0; kk < 256; ++kk) {
            float tk = Ts[kk];
            int k = base + kk;
            rank += (tk < tj || (tk == tj && k < g)) ? 1 : 0;
            kc   += (tk < thr) ? 1 : 0;
        }
        __syncthreads();
    }
    sorted_idx[rank] = g;
    kidx[g] = kc;
}

// K3: single-block two-level scan in sorted-t order.
// pre2[m][f]  = sum_{m'<m}  P2[s(m')] * Wh[s(m')][f]   (m in 0..N)
// suf1[m][f]  = sum_{m'>=m} P1[s(m')] * Wh[s(m')][f]   (m in 0..N, suf1[N]=0)
__global__ __launch_bounds__(1024) void k3_scan(
    const float* __restrict__ Wh, const float* __restrict__ PP,
    const int* __restrict__ sorted_idx,
    float* __restrict__ pre2, float* __restrict__ suf1)
{
    __shared__ int sidx[NN];
    __shared__ float tot1[16 * 64], tot2[16 * 64];
    int tid = threadIdx.x;
    for (int idx = tid; idx < NN; idx += 1024) sidx[idx] = sorted_idx[idx];
    __syncthreads();
    int f = tid & 63, wv = tid >> 6;
    int m0 = wv * 512;
    float t1 = 0.f, t2 = 0.f;
    for (int m = m0; m < m0 + 512; ++m) {
        int sj = sidx[m];
        float wh = Wh[(size_t)sj * 64 + f];
        t1 += PP[2 * sj] * wh;
        t2 += PP[2 * sj + 1] * wh;
    }
    tot1[wv * 64 + f] = t1; tot2[wv * 64 + f] = t2;
    __syncthreads();
    float off2 = 0.f;
    #pragma unroll
    for (int w = 0; w < 16; ++w) if (w < wv) off2 += tot2[w * 64 + f];
    float run = off2;
    for (int m = m0; m < m0 + 512; ++m) {
        pre2[(size_t)m * 64 + f] = run;
        int sj = sidx[m];
        run += PP[2 * sj + 1] * Wh[(size_t)sj * 64 + f];
    }
    if (wv == 15) pre2[(size_t)NN * 64 + f] = run;
    float off1 = 0.f;
    #pragma unroll
    for (int w = 0; w < 16; ++w) if (w > wv) off1 += tot1[w * 64 + f];
    run = off1;
    for (int m = m0 + 511; m >= m0; --m) {
        int sj = sidx[m];
        run += PP[2 * sj] * Wh[(size_t)sj * 64 + f];
        suf1[(size_t)m * 64 + f] = run;
    }
    if (tid < 64) suf1[(size_t)NN * 64 + tid] = 0.f;
}

// K4: denom[i] = E1_i * sum_{j in adj, cond} P1_j + E2_i * sum_{j in adj, !cond} P2_j
// cond = (s_i + t_j >= 0)  <=>  E1_i * P1_j >= 1 (exp monotone; boundary-continuous).
// Streams all of A (268 MB) with int4 loads; 8 rows per block amortize PP.
__global__ __launch_bounds__(256) void k4_denom(
    const int* __restrict__ A, const float* __restrict__ PP,
    const float* __restrict__ E1, const float* __restrict__ E2,
    float* __restrict__ denom)
{
    int tid = threadIdx.x;
    int i0 = blockIdx.x * 8;
    float e1r[8], accA[8], accB[8];
    #pragma unroll
    for (int r = 0; r < 8; ++r) { e1r[r] = E1[i0 + r]; accA[r] = 0.f; accB[r] = 0.f; }
    const float4* PPv = (const float4*)PP;
    for (int jv = tid; jv < NN / 4; jv += 256) {
        float4 ppA = PPv[2 * jv];       // P1[j], P2[j], P1[j+1], P2[j+1]
        float4 ppB = PPv[2 * jv + 1];   // P1[j+2], P2[j+2], P1[j+3], P2[j+3]
        #pragma unroll
        for (int r = 0; r < 8; ++r) {
            const int4 a4 = *(const int4*)(A + (size_t)(i0 + r) * NN + jv * 4);
            float e1 = e1r[r];
            {
                bool c = e1 * ppA.x >= 1.0f;
                float af = (float)a4.x;
                accA[r] += af * (c ? ppA.x : 0.0f);
                accB[r] += af * (c ? 0.0f : ppA.y);
            }
            {
                bool c = e1 * ppA.z >= 1.0f;
                float af = (float)a4.y;
                accA[r] += af * (c ? ppA.z : 0.0f);
                accB[r] += af * (c ? 0.0f : ppA.w);
            }
            {
                bool c = e1 * ppB.x >= 1.0f;
                float af = (float)a4.z;
                accA[r] += af * (c ? ppB.x : 0.0f);
                accB[r] += af * (c ? 0.0f : ppB.y);
            }
            {
                bool c = e1 * ppB.z >= 1.0f;
                float af = (float)a4.w;
                accA[r] += af * (c ? ppB.z : 0.0f);
                accB[r] += af * (c ? 0.0f : ppB.w);
            }
        }
    }
    #pragma unroll
    for (int r = 0; r < 8; ++r) {
        #pragma unroll
        for (int o = 32; o > 0; o >>= 1) {
            accA[r] += __shfl_xor(accA[r], o);
            accB[r] += __shfl_xor(accB[r], o);
        }
    }
    __shared__ float red[4][8][2];
    int wv = tid >> 6;
    if ((tid & 63) == 0) {
        #pragma unroll
        for (int r = 0; r < 8; ++r) { red[wv][r][0] = accA[r]; red[wv][r][1] = accB[r]; }
    }
    __syncthreads();
    if (tid < 8) {
        float sA = red[0][tid][0] + red[1][tid][0] + red[2][tid][0] + red[3][tid][0];
        float sB = red[0][tid][1] + red[1][tid][1] + red[2][tid][1] + red[3][tid][1];
        denom[i0 + tid] = E1[i0 + tid] * sA + E2[i0 + tid] * sB;
    }
}

// K5: out[i][f] = sigmoid( (E1_i*suf1[k_i][f] + E2_i*pre2[k_i][f]) / denom[i] )
__global__ __launch_bounds__(256) void k5_out(
    const float* __restrict__ suf1, const float* __restrict__ pre2,
    const int* __restrict__ kidx, const float* __restrict__ E1,
    const float* __restrict__ E2, const float* __restrict__ denom,
    float* __restrict__ out)
{
    int tid = threadIdx.x;
    int f = tid & 63, sub = tid >> 6;
    int i = blockIdx.x * 4 + sub;
    int k = kidx[i];
    float num = E1[i] * suf1[(size_t)k * 64 + f] + E2[i] * pre2[(size_t)k * 64 + f];
    float x = num / denom[i];
    out[(size_t)i * 64 + f] = 1.0f / (1.0f + __expf(-x));
}

extern "C" void kernel_launch(void* const* d_in, const int* in_sizes, int n_in,
                              void* d_out, int out_size, void* d_ws, size_t ws_size,
                              hipStream_t stream) {
    const float* H  = (const float*)d_in[0];
    const int*   A  = (const int*)d_in[1];
    const float* W  = (const float*)d_in[2];
    const float* bW = (const float*)d_in[3];
    const float* aw = (const float*)d_in[4];
    const float* ab = (const float*)d_in[5];
    float* out = (float*)d_out;

    float* ws    = (float*)d_ws;
    float* Wh    = ws;                    // 524288 floats
    float* s_src = Wh + 524288;           // 8192
    float* t_tar = s_src + 8192;          // 8192
    float* E1    = t_tar + 8192;          // 8192
    float* E2    = E1 + 8192;             // 8192
    float* PP    = E2 + 8192;             // 16384 (interleaved P1,P2)
    float* denom = PP + 16384;            // 8192
    float* pre2  = denom + 8192;          // 524352 ((N+1)*64)
    float* suf1  = pre2 + 524352;         // 524352
    int* sorted_idx = (int*)(suf1 + 524352);  // 8192 ints
    int* kidx       = sorted_idx + 8192;      // 8192 ints
    // total ~6.6 MB of d_ws

    hipLaunchKernelGGL(k1_proj, dim3(512), dim3(256), 0, stream,
                       H, W, bW, aw, ab, Wh, s_src, t_tar, E1, E2, PP);
    hipLaunchKernelGGL(k2_rank, dim3(32), dim3(256), 0, stream,
                       t_tar, s_src, sorted_idx, kidx);
    hipLaunchKernelGGL(k3_scan, dim3(1), dim3(1024), 0, stream,
                       Wh, PP, sorted_idx, pre2, suf1);
    hipLaunchKernelGGL(k4_denom, dim3(1024), dim3(256), 0, stream,
                       A, PP, E1, E2, denom);
    hipLaunchKernelGGL(k5_out, dim3(2048), dim3(256), 0, stream,
                       suf1, pre2, kidx, E1, E2, denom, out);
}

// Round 2
// 418.197 us; speedup vs baseline: 2.0167x; 2.0167x over previous
//
#include <hip/hip_runtime.h>
#include <hip/hip_bf16.h>

#define NN 8192
#define FIN 256
#define FOUT 64

// K1: Wh = H@W + bW; s = Wh.a1 + a_b; t = Wh.a2; exps + interleaved PP=(e^t, e^.01t).
__global__ __launch_bounds__(256) void k1_proj(
    const float* __restrict__ H, const float* __restrict__ W,
    const float* __restrict__ bW, const float* __restrict__ aw,
    const float* __restrict__ ab,
    float* __restrict__ Wh, float* __restrict__ s_src, float* __restrict__ t_tar,
    float* __restrict__ E1, float* __restrict__ E2, float* __restrict__ PP)
{
    __shared__ float Hs[16 * FIN];
    int tid = threadIdx.x;
    int i0 = blockIdx.x * 16;
    const float4* Hv = (const float4*)(H + (size_t)i0 * FIN);
    float4* Hsv = (float4*)Hs;
    for (int idx = tid; idx < 16 * FIN / 4; idx += 256) Hsv[idx] = Hv[idx];
    __syncthreads();
    int f = tid & 63, sub = tid >> 6;
    float a1f = aw[f], a2f = aw[64 + f];
    float b = bW[f];
    float acc0 = b, acc1 = b, acc2 = b, acc3 = b;
    for (int k = 0; k < FIN; ++k) {
        float w = W[k * FOUT + f];
        acc0 += Hs[(sub     ) * FIN + k] * w;
        acc1 += Hs[(sub +  4) * FIN + k] * w;
        acc2 += Hs[(sub +  8) * FIN + k] * w;
        acc3 += Hs[(sub + 12) * FIN + k] * w;
    }
    float accs[4] = {acc0, acc1, acc2, acc3};
    #pragma unroll
    for (int q = 0; q < 4; ++q) {
        int i = i0 + sub + 4 * q;
        float a = accs[q];
        Wh[(size_t)i * FOUT + f] = a;
        float v1 = a * a1f, v2 = a * a2f;
        #pragma unroll
        for (int o = 32; o > 0; o >>= 1) {
            v1 += __shfl_xor(v1, o);
            v2 += __shfl_xor(v2, o);
        }
        if (f == 0) {
            float s = v1 + ab[0];
            float t = v2;
            s_src[i] = s; t_tar[i] = t;
            E1[i] = __expf(s); E2[i] = __expf(0.01f * s);
            PP[2 * i]     = __expf(t);
            PP[2 * i + 1] = __expf(0.01f * t);
        }
    }
}

// K2 v2: one wave per node g. 64 lanes split the 8192 t-values (LDS-staged),
// butterfly-reduce rank (ties by index) and threshold count.
__global__ __launch_bounds__(256) void k2_rank(
    const float* __restrict__ t_tar, const float* __restrict__ s_src,
    int* __restrict__ sorted_idx, int* __restrict__ kidx)
{
    __shared__ float Ts[NN];
    int tid = threadIdx.x;
    const float4* tv = (const float4*)t_tar;
    float4* Tsv = (float4*)Ts;
    for (int idx = tid; idx < NN / 4; idx += 256) Tsv[idx] = tv[idx];
    __syncthreads();
    int wv = tid >> 6, lane = tid & 63;
    int g = blockIdx.x * 4 + wv;
    float tj = Ts[g];
    float thr = -s_src[g];
    int rank = 0, kc = 0;
    #pragma unroll 4
    for (int k = lane; k < NN; k += 64) {
        float tk = Ts[k];
        rank += (tk < tj || (tk == tj && k < g)) ? 1 : 0;
        kc   += (tk < thr) ? 1 : 0;
    }
    #pragma unroll
    for (int o = 32; o > 0; o >>= 1) {
        rank += __shfl_xor(rank, o);
        kc   += __shfl_xor(kc, o);
    }
    if (lane == 0) { sorted_idx[rank] = g; kidx[g] = kc; }
}

// K3 phase A: per-chunk (32 m's) totals of v1 = P1*Wh and v2 = P2*Wh in sorted order.
__global__ __launch_bounds__(64) void k3a_tots(
    const float* __restrict__ Wh, const float* __restrict__ PP,
    const int* __restrict__ sorted_idx,
    float* __restrict__ tots1, float* __restrict__ tots2)
{
    int c = blockIdx.x, f = threadIdx.x;
    float t1 = 0.f, t2 = 0.f;
    int m0 = c * 32;
    #pragma unroll 8
    for (int m = m0; m < m0 + 32; ++m) {
        int sj = sorted_idx[m];
        float wh = Wh[(size_t)sj * 64 + f];
        t1 += PP[2 * sj]     * wh;
        t2 += PP[2 * sj + 1] * wh;
    }
    tots1[c * 64 + f] = t1; tots2[c * 64 + f] = t2;
}

// K3 phase B: scan 256 chunk totals -> exclusive prefix (off2) / exclusive suffix (off1).
__global__ __launch_bounds__(1024) void k3b_scan(
    const float* __restrict__ tots1, const float* __restrict__ tots2,
    float* __restrict__ off1, float* __restrict__ off2,
    float* __restrict__ pre2, float* __restrict__ suf1)
{
    __shared__ float w1[16 * 64], w2[16 * 64];
    int tid = threadIdx.x, f = tid & 63, wv = tid >> 6;
    int c0 = wv * 16;
    float s1 = 0.f, s2 = 0.f;
    for (int c = c0; c < c0 + 16; ++c) { s1 += tots1[c * 64 + f]; s2 += tots2[c * 64 + f]; }
    w1[wv * 64 + f] = s1; w2[wv * 64 + f] = s2;
    __syncthreads();
    float o2 = 0.f;
    #pragma unroll
    for (int w = 0; w < 16; ++w) if (w < wv) o2 += w2[w * 64 + f];
    float run2 = o2;
    for (int c = c0; c < c0 + 16; ++c) { off2[c * 64 + f] = run2; run2 += tots2[c * 64 + f]; }
    if (wv == 15) pre2[(size_t)NN * 64 + f] = run2;   // full prefix total
    float o1 = 0.f;
    #pragma unroll
    for (int w = 0; w < 16; ++w) if (w > wv) o1 += w1[w * 64 + f];
    float run1 = o1;
    for (int c = c0 + 15; c >= c0; --c) { off1[c * 64 + f] = run1; run1 += tots1[c * 64 + f]; }
    if (tid < 64) suf1[(size_t)NN * 64 + tid] = 0.f;
}

// K3 phase C: emit pre2/suf1 within each chunk from the offsets.
__global__ __launch_bounds__(64) void k3c_emit(
    const float* __restrict__ Wh, const float* __restrict__ PP,
    const int* __restrict__ sorted_idx,
    const float* __restrict__ off1, const float* __restrict__ off2,
    float* __restrict__ pre2, float* __restrict__ suf1)
{
    int c = blockIdx.x, f = threadIdx.x;
    int m0 = c * 32;
    float whr[32], p1r[32], p2r[32];
    #pragma unroll
    for (int q = 0; q < 32; ++q) {
        int sj = sorted_idx[m0 + q];
        whr[q] = Wh[(size_t)sj * 64 + f];
        p1r[q] = PP[2 * sj]; p2r[q] = PP[2 * sj + 1];
    }
    float run2 = off2[c * 64 + f];
    #pragma unroll
    for (int q = 0; q < 32; ++q) {
        pre2[(size_t)(m0 + q) * 64 + f] = run2;
        run2 += p2r[q] * whr[q];
    }
    float run1 = off1[c * 64 + f];
    #pragma unroll
    for (int q = 31; q >= 0; --q) {
        run1 += p1r[q] * whr[q];
        suf1[(size_t)(m0 + q) * 64 + f] = run1;
    }
}

// K4: denom[i] = E1_i * Σ_{adj, cond} P1_j + E2_i * Σ_{adj, !cond} P2_j
// cond = (s_i + t_j >= 0)  <=>  E1_i * P1_j >= 1. Streams A (268 MB) with int4.
__global__ __launch_bounds__(256) void k4_denom(
    const int* __restrict__ A, const float* __restrict__ PP,
    const float* __restrict__ E1, const float* __restrict__ E2,
    float* __restrict__ denom)
{
    int tid = threadIdx.x;
    int i0 = blockIdx.x * 8;
    float e1r[8], accA[8], accB[8];
    #pragma unroll
    for (int r = 0; r < 8; ++r) { e1r[r] = E1[i0 + r]; accA[r] = 0.f; accB[r] = 0.f; }
    const float4* PPv = (const float4*)PP;
    for (int jv = tid; jv < NN / 4; jv += 256) {
        float4 ppA = PPv[2 * jv];
        float4 ppB = PPv[2 * jv + 1];
        #pragma unroll
        for (int r = 0; r < 8; ++r) {
            const int4 a4 = *(const int4*)(A + (size_t)(i0 + r) * NN + jv * 4);
            float e1 = e1r[r];
            {
                bool c = e1 * ppA.x >= 1.0f;
                float af = (float)a4.x;
                accA[r] += af * (c ? ppA.x : 0.0f);
                accB[r] += af * (c ? 0.0f : ppA.y);
            }
            {
                bool c = e1 * ppA.z >= 1.0f;
                float af = (float)a4.y;
                accA[r] += af * (c ? ppA.z : 0.0f);
                accB[r] += af * (c ? 0.0f : ppA.w);
            }
            {
                bool c = e1 * ppB.x >= 1.0f;
                float af = (float)a4.z;
                accA[r] += af * (c ? ppB.x : 0.0f);
                accB[r] += af * (c ? 0.0f : ppB.y);
            }
            {
                bool c = e1 * ppB.z >= 1.0f;
                float af = (float)a4.w;
                accA[r] += af * (c ? ppB.z : 0.0f);
                accB[r] += af * (c ? 0.0f : ppB.w);
            }
        }
    }
    #pragma unroll
    for (int r = 0; r < 8; ++r) {
        #pragma unroll
        for (int o = 32; o > 0; o >>= 1) {
            accA[r] += __shfl_xor(accA[r], o);
            accB[r] += __shfl_xor(accB[r], o);
        }
    }
    __shared__ float red[4][8][2];
    int wv = tid >> 6;
    if ((tid & 63) == 0) {
        #pragma unroll
        for (int r = 0; r < 8; ++r) { red[wv][r][0] = accA[r]; red[wv][r][1] = accB[r]; }
    }
    __syncthreads();
    if (tid < 8) {
        float sA = red[0][tid][0] + red[1][tid][0] + red[2][tid][0] + red[3][tid][0];
        float sB = red[0][tid][1] + red[1][tid][1] + red[2][tid][1] + red[3][tid][1];
        denom[i0 + tid] = E1[i0 + tid] * sA + E2[i0 + tid] * sB;
    }
}

// K5: out[i][f] = sigmoid( (E1_i*suf1[k_i][f] + E2_i*pre2[k_i][f]) / denom[i] )
__global__ __launch_bounds__(256) void k5_out(
    const float* __restrict__ suf1, const float* __restrict__ pre2,
    const int* __restrict__ kidx, const float* __restrict__ E1,
    const float* __restrict__ E2, const float* __restrict__ denom,
    float* __restrict__ out)
{
    int tid = threadIdx.x;
    int f = tid & 63, sub = tid >> 6;
    int i = blockIdx.x * 4 + sub;
    int k = kidx[i];
    float num = E1[i] * suf1[(size_t)k * 64 + f] + E2[i] * pre2[(size_t)k * 64 + f];
    float x = num / denom[i];
    out[(size_t)i * 64 + f] = 1.0f / (1.0f + __expf(-x));
}

extern "C" void kernel_launch(void* const* d_in, const int* in_sizes, int n_in,
                              void* d_out, int out_size, void* d_ws, size_t ws_size,
                              hipStream_t stream) {
    const float* H  = (const float*)d_in[0];
    const int*   A  = (const int*)d_in[1];
    const float* W  = (const float*)d_in[2];
    const float* bW = (const float*)d_in[3];
    const float* aw = (const float*)d_in[4];
    const float* ab = (const float*)d_in[5];
    float* out = (float*)d_out;

    float* ws    = (float*)d_ws;
    float* Wh    = ws;                    // 524288
    float* s_src = Wh + 524288;           // 8192
    float* t_tar = s_src + 8192;          // 8192
    float* E1    = t_tar + 8192;          // 8192
    float* E2    = E1 + 8192;             // 8192
    float* PP    = E2 + 8192;             // 16384
    float* denom = PP + 16384;            // 8192
    float* pre2  = denom + 8192;          // 524352 ((N+1)*64)
    float* suf1  = pre2 + 524352;         // 524352
    float* tots1 = suf1 + 524352;         // 16384 (256*64)
    float* tots2 = tots1 + 16384;         // 16384
    float* off1  = tots2 + 16384;         // 16384
    float* off2  = off1 + 16384;          // 16384
    int* sorted_idx = (int*)(off2 + 16384);   // 8192 ints
    int* kidx       = sorted_idx + 8192;      // 8192 ints

    hipLaunchKernelGGL(k1_proj, dim3(512), dim3(256), 0, stream,
                       H, W, bW, aw, ab, Wh, s_src, t_tar, E1, E2, PP);
    hipLaunchKernelGGL(k2_rank, dim3(2048), dim3(256), 0, stream,
                       t_tar, s_src, sorted_idx, kidx);
    hipLaunchKernelGGL(k3a_tots, dim3(256), dim3(64), 0, stream,
                       Wh, PP, sorted_idx, tots1, tots2);
    hipLaunchKernelGGL(k3b_scan, dim3(1), dim3(1024), 0, stream,
                       tots1, tots2, off1, off2, pre2, suf1);
    hipLaunchKernelGGL(k3c_emit, dim3(256), dim3(64), 0, stream,
                       Wh, PP, sorted_idx, off1, off2, pre2, suf1);
    hipLaunchKernelGGL(k4_denom, dim3(1024), dim3(256), 0, stream,
                       A, PP, E1, E2, denom);
    hipLaunchKernelGGL(k5_out, dim3(2048), dim3(256), 0, stream,
                       suf1, pre2, kidx, E1, E2, denom, out);
}